// Round 11
// baseline (329.261 us; speedup 1.0000x reference)
//
#include <hip/hip_runtime.h>
#include <cmath>

typedef unsigned short u16;
typedef unsigned int u32;
typedef short frag8 __attribute__((ext_vector_type(8)));   // 8 bf16 = 4 VGPRs
typedef float f32x4 __attribute__((ext_vector_type(4)));

#define DEVINL __device__ __forceinline__

DEVINL float bf2f(u16 v) { return __uint_as_float(((u32)v) << 16); }
DEVINL u16 f2bf(float f) {
    u32 u = __float_as_uint(f);
    u32 r = (u + 0x7fffu + ((u >> 16) & 1u)) >> 16;   // RNE
    return (u16)r;
}
DEVINL u32 pack2(float a, float b) { return (u32)f2bf(a) | ((u32)f2bf(b) << 16); }
DEVINL void async_copy16(const u16* g, u16* l) {
    __builtin_amdgcn_global_load_lds((const __attribute__((address_space(1))) u32*)g,
                                     (__attribute__((address_space(3))) u32*)l, 16, 0, 0);
}
DEVINL f32x4 mfma_bf16(frag8 a, frag8 b, f32x4 c) {
    return __builtin_amdgcn_mfma_f32_16x16x32_bf16(a, b, c, 0, 0, 0);
}
// Counted VMEM wait (literal N). Memory clobber pins surrounding memory ops.
#define VMCNT(N) asm volatile("s_waitcnt vmcnt(" #N ")" ::: "memory")
// Raw barrier: orders LDS (lgkmcnt(0) + s_barrier) WITHOUT draining vmcnt —
// in-flight global loads cross it. Memory clobber also stops the compiler
// from sinking register loads past the barrier (prefetch issue is pinned).
DEVINL void bar_raw() {
    asm volatile("s_waitcnt lgkmcnt(0)" ::: "memory");
    __builtin_amdgcn_s_barrier();
    asm volatile("" ::: "memory");
}

// ------------------------------------------------------------------
// Kernel 0: f32 -> bf16 conversion of x, Wq, Wk, Wv, Wout into ws.
// ------------------------------------------------------------------
__global__ __launch_bounds__(256) void convert_kernel(
        const float* __restrict__ s0, const float* __restrict__ s1,
        const float* __restrict__ s2, const float* __restrict__ s3,
        const float* __restrict__ s4, u16* __restrict__ dst) {
    const int c0 = 589824, c1 = 98304, c2 = 98304, c3 = 294912;  // chunks of 8
    const int total = 1376256;
    for (int c = blockIdx.x * blockDim.x + threadIdx.x; c < total;
         c += gridDim.x * blockDim.x) {
        const float* src; int off;
        if (c < c0) { src = s0; off = c; }
        else if (c < c0 + c1) { src = s1; off = c - c0; }
        else if (c < c0 + c1 + c2) { src = s2; off = c - c0 - c1; }
        else if (c < c0 + c1 + c2 + c3) { src = s3; off = c - c0 - c1 - c2; }
        else { src = s4; off = c - c0 - c1 - c2 - c3; }
        float4 a = ((const float4*)src)[off * 2];
        float4 b = ((const float4*)src)[off * 2 + 1];
        uint4 o;
        o.x = pack2(a.x, a.y); o.y = pack2(a.z, a.w);
        o.z = pack2(b.x, b.y); o.w = pack2(b.z, b.w);
        ((uint4*)dst)[c] = o;
    }
}

// ------------------------------------------------------------------
// Kernel 1: positional embedding features fused with rel_k projection
// rel_k layout: [h][3072][64] bf16 (row 3071 = pad, computed anyway)
// ------------------------------------------------------------------
DEVINL double lgamma_stirling(double z) {
    double zi = 1.0 / z, zi2 = zi * zi;
    return (z - 0.5) * log(z) - z + 0.91893853320467274178
         + zi * (1.0 / 12.0) - zi * zi2 * (1.0 / 360.0) + zi * zi2 * zi2 * (1.0 / 1260.0);
}

__global__ __launch_bounds__(256) void embed_relk_kernel(const float* __restrict__ Wrel,
                                                         u16* __restrict__ relk) {
    __shared__ float pos[16][192];
    __shared__ float inv_hl[32], cwid[32], cm1[32], rateS[32];
    __shared__ double lognS[32];
    __shared__ float gmax[16];
    int t = threadIdx.x;
    int u0b = blockIdx.x * 16;

    if (t < 32) {
        double step = (10.584962500721156 - 3.0) / 31.0;   // log2(1536)
        double hl = exp2(3.0 + t * step);
        inv_hl[t] = (float)(1.0 / hl);
        cwid[t] = exp2f((float)(t + 1)) - 1.0f;            // 2^(t+1)-1
        double mean = 48.0 * (t + 1);                      // linspace(48,1536,32)
        double conc = (mean / 24.0) * (mean / 24.0);
        double rate = mean / 576.0;
        cm1[t] = (float)(conc - 1.0);
        rateS[t] = (float)rate;
        lognS[t] = lgamma_stirling(conc) - conc * log(rate);
    }
    __syncthreads();

    for (int idx = t; idx < 512; idx += 256) {
        int ul = idx >> 5, bs = idx & 31;
        int dist = u0b + ul - 1535;
        float ad = fabsf((float)dist);
        pos[ul][bs] = exp2f(-ad * inv_hl[bs]);
        pos[ul][32 + bs] = (cwid[bs] > ad) ? 1.0f : 0.0f;
        double prob = 0.0;
        if (dist != 0) {
            double adD = (double)ad;
            prob = exp((double)cm1[bs] * log(adD) - (double)rateS[bs] * adD - lognS[bs]);
        }
        pos[ul][64 + bs] = (float)(prob + 1e-8);
    }
    __syncthreads();
    if (t < 16) {
        float g = 0.f;
        #pragma unroll
        for (int bsx = 0; bsx < 32; bsx++) g = fmaxf(g, pos[t][64 + bsx]);
        gmax[t] = g;
    }
    __syncthreads();
    for (int idx = t; idx < 16 * 96; idx += 256) {
        int ul = idx / 96, f = idx - ul * 96;
        float v = pos[ul][f];
        if (f >= 64) { v = v / gmax[ul]; pos[ul][f] = v; }
        int dist = u0b + ul - 1535;
        float sg = (dist > 0) ? 1.f : ((dist < 0) ? -1.f : 0.f);
        pos[ul][96 + f] = sg * v;
    }
    __syncthreads();

    // project: rel_k[u][e] = sum_f pos[u][f] * Wrel[e][f]; thread owns 2 e-cols
    int e0 = t * 2;
    const float* w0 = Wrel + e0 * 192;
    const float* w1 = w0 + 192;
    float a0[16], a1[16];
    #pragma unroll
    for (int ul = 0; ul < 16; ul++) { a0[ul] = 0.f; a1[ul] = 0.f; }
    for (int f = 0; f < 192; f++) {
        float wa = w0[f], wb = w1[f];
        #pragma unroll
        for (int ul = 0; ul < 16; ul++) {
            float p = pos[ul][f];
            a0[ul] = fmaf(p, wa, a0[ul]);
            a1[ul] = fmaf(p, wb, a1[ul]);
        }
    }
    int h0 = e0 >> 6, d0 = e0 & 63;
    int h1 = (e0 + 1) >> 6, d1 = (e0 + 1) & 63;
    for (int ul = 0; ul < 16; ul++) {
        int u = u0b + ul;
        relk[(h0 * 3072 + u) * 64 + d0] = f2bf(a0[ul]);
        relk[(h1 * 3072 + u) * 64 + d1] = f2bf(a1[ul]);
    }
}

// ------------------------------------------------------------------
// Shared 128x128 BT-GEMM mainloop, K contiguous in both operands.
// Ring-4 LDS buffers, DEPTH-3 counted-vmcnt prefetch (verified r7).
// Identity block mapping (r10: chunked swizzle neutral within noise).
// ------------------------------------------------------------------
DEVINL void gemm128_stage(const u16* __restrict__ A, const u16* __restrict__ B,
                          int K, int k0, u16* buf, int tid) {
    #pragma unroll
    for (int p = 0; p < 2; p++) {     // 4 loads/thread (2 A + 2 B)
        int e = (p * 256 + tid) * 8;
        int r = e >> 5, c = e & 31;
        async_copy16(A + r * K + k0 + c, buf + e);            // As @ buf
        async_copy16(B + r * K + k0 + c, buf + 4096 + e);     // Bs @ buf+4096
    }
}

DEVINL void gemm128_mainloop(const u16* __restrict__ A, const u16* __restrict__ B,
                             int K, f32x4 acc[4][4], u16* smem) {
    int tid = threadIdx.x;
    int lane = tid & 63, wave = tid >> 6;
    int wm = (wave >> 1) * 64, wn = (wave & 1) * 64;
    int fm = lane & 15, fq = lane >> 4;
    const int NT = K >> 5;   // 48
    gemm128_stage(A, B, K, 0,  smem,         tid);   // prologue: 3 tiles
    gemm128_stage(A, B, K, 32, smem + 8192,  tid);   // in flight (12 loads)
    gemm128_stage(A, B, K, 64, smem + 16384, tid);
    for (int t = 0; t < NT; t++) {
        u16* cur = smem + (t & 3) * 8192;
        if (t + 3 < NT) {
            gemm128_stage(A, B, K, (t + 3) * 32, smem + ((t + 3) & 3) * 8192, tid);
            VMCNT(12);    // tile t landed; t+1..t+3 (12 loads) in flight
        } else if (t + 2 < NT) {
            VMCNT(8);
        } else if (t + 1 < NT) {
            VMCNT(4);
        } else {
            VMCNT(0);
        }
        bar_raw();        // every wave waited its own loads -> tile visible
        frag8 af[4], bfr[4];
        #pragma unroll
        for (int mi = 0; mi < 4; mi++) af[mi] = *(const frag8*)&cur[(wm + 16 * mi + fm) * 32 + fq * 8];
        #pragma unroll
        for (int ni = 0; ni < 4; ni++) bfr[ni] = *(const frag8*)&cur[4096 + (wn + 16 * ni + fm) * 32 + fq * 8];
        #pragma unroll
        for (int mi = 0; mi < 4; mi++)
            #pragma unroll
            for (int ni = 0; ni < 4; ni++)
                acc[mi][ni] = mfma_bf16(af[mi], bfr[ni], acc[mi][ni]);
        bar_raw();        // reads done; iter t+1 may overwrite buf[(t+4)&3]
    }
}

// ------------------------------------------------------------------
// Kernel 2: fused QKV projection. N=2560 = [q 512 | k 512 | v 1536]
// qc/qp/k layout [b][h][n][64]; V stored transposed [b][h][192][n]
// ------------------------------------------------------------------
__global__ __launch_bounds__(256) void gemm_qkv_kernel(
        const u16* __restrict__ X, const u16* __restrict__ Wq, const u16* __restrict__ Wk,
        const u16* __restrict__ Wv, const float* __restrict__ cbias, const float* __restrict__ pbias,
        u16* __restrict__ qc, u16* __restrict__ qp, u16* __restrict__ kws, u16* __restrict__ vt) {
    __shared__ __align__(16) u16 smem[32768];   // 4 ring buffers x 16 KB
    int m0 = blockIdx.x * 128, n0 = blockIdx.y * 128;
    const u16* Bp; int brow;
    if (n0 < 512)       { Bp = Wq; brow = n0; }
    else if (n0 < 1024) { Bp = Wk; brow = n0 - 512; }
    else                { Bp = Wv; brow = n0 - 1024; }
    f32x4 acc[4][4];
    #pragma unroll
    for (int i = 0; i < 4; i++)
        #pragma unroll
        for (int j = 0; j < 4; j++) acc[i][j] = (f32x4){0.f, 0.f, 0.f, 0.f};
    gemm128_mainloop(X + m0 * 1536, Bp + brow * 1536, 1536, acc, smem);

    int tid = threadIdx.x, lane = tid & 63, wave = tid >> 6;
    int wm = (wave >> 1) * 64, wn = (wave & 1) * 64, fm = lane & 15, fq = lane >> 4;
    #pragma unroll
    for (int mi = 0; mi < 4; mi++) {
        #pragma unroll
        for (int ni = 0; ni < 4; ni++) {
            int col = n0 + wn + 16 * ni + fm;
            int rbase = m0 + wm + 16 * mi + fq * 4;
            #pragma unroll
            for (int reg = 0; reg < 4; reg++) {
                int row = rbase + reg;
                float v = acc[mi][ni][reg];
                int b = row >= 1536 ? 1 : 0;
                int i = row - b * 1536;
                if (n0 < 512) {
                    float qv = v * 0.125f;
                    int idx = ((b * 8 + (col >> 6)) * 1536 + i) * 64 + (col & 63);
                    qc[idx] = f2bf(qv + cbias[col]);
                    qp[idx] = f2bf(qv + pbias[col]);
                } else if (n0 < 1024) {
                    int c2 = col - 512;
                    kws[((b * 8 + (c2 >> 6)) * 1536 + i) * 64 + (c2 & 63)] = f2bf(v);
                } else {
                    int c2 = col - 1024;
                    int hh = c2 / 192, dd = c2 - hh * 192;
                    vt[((b * 8 + hh) * 192 + dd) * 1536 + i] = f2bf(v);
                }
            }
        }
    }
}

// ------------------------------------------------------------------
// Kernel 3: flash attention with relative-shift band. Round-11:
// THE ATTN KERNEL IS LDS-ISSUE-BOUND (r10 arithmetic: ~4400 LDS-unit
// cyc/CU/iter vs 3765 observed; MFMA/VALU/HBM all idle). Fix: move all
// MFMA B-operand traffic (K, relk, V) off the LDS unit onto the idle
// VMEM pipe — direct global->register loads, NO K/relk LDS staging:
//  - fk/fr(t+1) issue right after their last use (phase-1 MFMAs of t),
//    in flight across both barriers (~1000 cyc) -> land before next use.
//    bar_raw's memory clobber pins their issue before B4.
//  - fv(t) issues at iteration top, consumed in PV (r8 pattern, works).
//  - All plain C loads: compiler emits precise counted vmcnt waits.
//  - K: zero cross-wave sharing (wave w reads rows 16w+fm only).
//    relk: <=2-way sharing, L2-resident (FETCH +~1MB acceptable).
//  - LDS now holds ONLY the unavoidable cross-wave exchange:
//    S/R (padded f32), P, softmax state = 26 KB.
//  - TWO raw barriers/iter (r2's hazard proof):
//    B4: S/R writes visible for softmax; also separates PV's P/alpha
//        reads(t-1) from softmax's P/alpha writes(t).
//    B5: P/alpha visible for PV; also separates softmax's S/R reads(t)
//        from next iter's S/R writes(t+1).
//    mstate/lstate row li: 8 threads of ONE wave -> lockstep. SAFE.
//  - plain __launch_bounds__(256): r1/r3 failed ONLY via allocator caps
//    (64-VGPR remat at cap 128; spill at cap 170). r8 held 24 prefetch
//    VGPRs cleanly at 108 with the plain bound. Health: WRITE_SIZE must
//    stay 9216 (no spill), VGPR 130-180.
// ------------------------------------------------------------------
#define SP 68    // S row stride (f32)
#define RP 100   // R row stride (f32)

__global__ __launch_bounds__(256) void attn_kernel(
        const u16* __restrict__ qc, const u16* __restrict__ qp, const u16* __restrict__ kws,
        const u16* __restrict__ vt, const u16* __restrict__ relk, u16* __restrict__ ao) {
    // carve (u16): P 2048 | S 32*68 f32 (4352) | R 32*100 f32 (6400) |
    //              state 192  => 12992 u16 = 25984 B
    __shared__ __align__(16) u16 smem[12992];
    u16* P_lds    = smem;                     // [32][64] chunk-swizzled
    float* S_lds  = (float*)(smem + 2048);    // [32][SP]
    float* R_lds  = (float*)(smem + 6400);    // [32][RP]
    float* mstate = (float*)(smem + 12800);   // [32]
    float* lstate = mstate + 32;
    float* alpha_lds = lstate + 32;

    const int n = 1536;
    // XCD-aware swizzle (bijective: 768 % 8 == 0): XCD c owns bh {2c,2c+1}
    // -> per-XCD L2 working set ~3.1 MB. [verified r3/r4: FETCH 74->12.4 MB]
    int flat = blockIdx.y * 48 + blockIdx.x;
    int swz  = (flat & 7) * 96 + (flat >> 3);
    int bh = swz / 48;
    int i0 = (swz - bh * 48) * 32;
    int b = bh >> 3, h = bh & 7;
    const u16* qcP = qc + bh * n * 64;
    const u16* qpP = qp + bh * n * 64;
    const u16* kP  = kws + bh * n * 64;
    const u16* vtP = vt + bh * 192 * n;
    const u16* rkP = relk + h * 3072 * 64;

    int tid = threadIdx.x, lane = tid & 63, w = tid >> 6, fm = lane & 15, fq = lane >> 4;
    int sw = fm & 7;   // xor-swizzle key for P chunks
    if (tid < 32) { mstate[tid] = __int_as_float(0xff800000); lstate[tid] = 0.f; }

    // Q fragments live in registers for the whole block
    frag8 aqc[2][2], aqp[2][2];
    #pragma unroll
    for (int mi = 0; mi < 2; mi++)
        #pragma unroll
        for (int ks = 0; ks < 2; ks++) {
            int off = (i0 + 16 * mi + fm) * 64 + ks * 32 + fq * 8;
            aqc[mi][ks] = *(const frag8*)(qcP + off);
            aqp[mi][ks] = *(const frag8*)(qpP + off);
        }

    f32x4 acc_o[2][3];
    #pragma unroll
    for (int mi = 0; mi < 2; mi++)
        #pragma unroll
        for (int dj = 0; dj < 3; dj++) acc_o[mi][dj] = (f32x4){0.f, 0.f, 0.f, 0.f};

    // R-tile ownership: tv = w + 4tt -> (ui = tv%6, rmi = tv/6)
    int uis[3], rmis[3];
    #pragma unroll
    for (int tt = 0; tt < 3; tt++) {
        int tv = w + tt * 4;
        rmis[tt] = (tv >= 6) ? 1 : 0;
        uis[tt] = tv - rmis[tt] * 6;
    }

    // per-lane global fragment pointers (advance 64 rows = 4096 u16 per tile)
    const u16* kIt = kP + (16 * w + fm) * 64 + fq * 8;
    const u16* rIt0 = rkP + (1504 - i0 + 16 * uis[0] + fm) * 64 + fq * 8;
    const u16* rIt1 = rkP + (1504 - i0 + 16 * uis[1] + fm) * 64 + fq * 8;
    const u16* rIt2 = rkP + (1504 - i0 + 16 * uis[2] + fm) * 64 + fq * 8;
    const u16* vBase = vtP + (48 * w + fm) * 1536 + fq * 8;

    // ---- prologue: prefetch tile 0's K + relk fragments (registers) ----
    frag8 fk[2], fr0[2], fr1[2], fr2[2];
    fk[0]  = *(const frag8*)(kIt);       fk[1]  = *(const frag8*)(kIt + 32);
    fr0[0] = *(const frag8*)(rIt0);      fr0[1] = *(const frag8*)(rIt0 + 32);
    fr1[0] = *(const frag8*)(rIt1);      fr1[1] = *(const frag8*)(rIt1 + 32);
    fr2[0] = *(const frag8*)(rIt2);      fr2[1] = *(const frag8*)(rIt2 + 32);
    kIt += 4096; rIt0 += 4096; rIt1 += 4096; rIt2 += 4096;

    for (int jt = 0; jt < 24; jt++) {
        int j0 = jt * 64;
        // ---- V(t) -> registers, issued at top; consumed in PV (~3 phases) ----
        frag8 fv[3][2];
        #pragma unroll
        for (int dj = 0; dj < 3; dj++)
            #pragma unroll
            for (int ks = 0; ks < 2; ks++)
                fv[dj][ks] = *(const frag8*)(vBase + dj * 16 * 1536 + j0 + ks * 32);

        // ---- phase 1: content + rel logits (prefetched K/relk regs) ----
        f32x4 acc_s[2];
        acc_s[0] = (f32x4){0.f, 0.f, 0.f, 0.f};
        acc_s[1] = (f32x4){0.f, 0.f, 0.f, 0.f};
        #pragma unroll
        for (int ks = 0; ks < 2; ks++) {
            acc_s[0] = mfma_bf16(aqc[0][ks], fk[ks], acc_s[0]);
            acc_s[1] = mfma_bf16(aqc[1][ks], fk[ks], acc_s[1]);
        }
        f32x4 acc_r[3];
        #pragma unroll
        for (int tt = 0; tt < 3; tt++) acc_r[tt] = (f32x4){0.f, 0.f, 0.f, 0.f};
        #pragma unroll
        for (int ks = 0; ks < 2; ks++) {
            acc_r[0] = mfma_bf16(aqp[rmis[0]][ks], fr0[ks], acc_r[0]);
            acc_r[1] = mfma_bf16(aqp[rmis[1]][ks], fr1[ks], acc_r[1]);
            acc_r[2] = mfma_bf16(aqp[rmis[2]][ks], fr2[ks], acc_r[2]);
        }

        // ---- prefetch K/relk(t+1) right after last use; loads fly across
        //      B4+B5+softmax+PV (~1000 cyc) before next phase-1 use ----
        if (jt < 23) {
            fk[0]  = *(const frag8*)(kIt);   fk[1]  = *(const frag8*)(kIt + 32);
            fr0[0] = *(const frag8*)(rIt0);  fr0[1] = *(const frag8*)(rIt0 + 32);
            fr1[0] = *(const frag8*)(rIt1);  fr1[1] = *(const frag8*)(rIt1 + 32);
            fr2[0] = *(const frag8*)(rIt2);  fr2[1] = *(const frag8*)(rIt2 + 32);
            kIt += 4096; rIt0 += 4096; rIt1 += 4096; rIt2 += 4096;
        }

        // ---- phase 2: S/R exchange (padded strides; 2-way alias max) ----
        #pragma unroll
        for (int mi = 0; mi < 2; mi++)
            #pragma unroll
            for (int reg = 0; reg < 4; reg++)
                S_lds[(16 * mi + fq * 4 + reg) * SP + 16 * w + fm] = acc_s[mi][reg];
        #pragma unroll
        for (int tt = 0; tt < 3; tt++)
            #pragma unroll
            for (int reg = 0; reg < 4; reg++)
                R_lds[(16 * rmis[tt] + fq * 4 + reg) * RP + 16 * uis[tt] + fm] = acc_r[tt][reg];
        bar_raw();         // B4: S/R visible; prior PV's P/alpha reads done

        // ---- phase 3: online softmax, 8 threads per row ----
        int li = tid >> 3, c0 = (tid & 7) * 8;
        float sv[8];
        {
            float4 sa = *(const float4*)(S_lds + li * SP + c0);
            float4 sb = *(const float4*)(S_lds + li * SP + c0 + 4);
            sv[0] = sa.x; sv[1] = sa.y; sv[2] = sa.z; sv[3] = sa.w;
            sv[4] = sb.x; sv[5] = sb.y; sv[6] = sb.z; sv[7] = sb.w;
        }
        const float* rrow = R_lds + li * RP + c0 - li + 31;
        float mx = __int_as_float(0xff800000);
        #pragma unroll
        for (int e = 0; e < 8; e++) {
            sv[e] += rrow[e];
            mx = fmaxf(mx, sv[e]);
        }
        mx = fmaxf(mx, __shfl_xor(mx, 1));
        mx = fmaxf(mx, __shfl_xor(mx, 2));
        mx = fmaxf(mx, __shfl_xor(mx, 4));
        float mo = mstate[li];
        float mn = fmaxf(mo, mx);
        float al = __expf(mo - mn);
        float pe[8], sum = 0.f;
        #pragma unroll
        for (int e = 0; e < 8; e++) { pe[e] = __expf(sv[e] - mn); sum += pe[e]; }
        {
            uint4 pw;
            pw.x = pack2(pe[0], pe[1]); pw.y = pack2(pe[2], pe[3]);
            pw.z = pack2(pe[4], pe[5]); pw.w = pack2(pe[6], pe[7]);
            int slot = (tid & 7) ^ (li & 7);
            *(uint4*)&P_lds[li * 64 + slot * 8] = pw;
        }
        sum += __shfl_xor(sum, 1);
        sum += __shfl_xor(sum, 2);
        sum += __shfl_xor(sum, 4);
        if ((tid & 7) == 0) {
            mstate[li] = mn;
            lstate[li] = lstate[li] * al + sum;
            alpha_lds[li] = al;
        }
        bar_raw();         // B5: P, alpha visible

        // ---- phase 4: PV from P_lds + V registers ----
        #pragma unroll
        for (int mi = 0; mi < 2; mi++)
            #pragma unroll
            for (int reg = 0; reg < 4; reg++) {
                float al2 = alpha_lds[16 * mi + fq * 4 + reg];
                #pragma unroll
                for (int dj = 0; dj < 3; dj++) acc_o[mi][dj][reg] *= al2;
            }
        frag8 ap[2][2];
        #pragma unroll
        for (int mi = 0; mi < 2; mi++)
            #pragma unroll
            for (int ks = 0; ks < 2; ks++)
                ap[mi][ks] = *(const frag8*)&P_lds[(16 * mi + fm) * 64 + ((ks * 4 + fq) ^ sw) * 8];
        #pragma unroll
        for (int dj = 0; dj < 3; dj++) {
            #pragma unroll
            for (int ks = 0; ks < 2; ks++) {
                acc_o[0][dj] = mfma_bf16(ap[0][ks], fv[dj][ks], acc_o[0][dj]);
                acc_o[1][dj] = mfma_bf16(ap[1][ks], fv[dj][ks], acc_o[1][dj]);
            }
        }
    }

    // epilogue: O / l -> ao[b*1536 + i][h*192 + dv]
    // (lstate final writes precede final B5 -> visible here)
    #pragma unroll
    for (int mi = 0; mi < 2; mi++)
        #pragma unroll
        for (int dj = 0; dj < 3; dj++)
            #pragma unroll
            for (int reg = 0; reg < 4; reg++) {
                int rl = 16 * mi + fq * 4 + reg;
                float lsum = lstate[rl];
                int row = b * 1536 + i0 + rl;
                int col = h * 192 + 16 * (3 * w + dj) + fm;
                ao[row * 1536 + col] = f2bf(acc_o[mi][dj][reg] / lsum);
            }
}

// ------------------------------------------------------------------
// Kernel 4: output projection + bias (f32 out)
// ------------------------------------------------------------------
__global__ __launch_bounds__(256) void gemm_out_kernel(
        const u16* __restrict__ A, const u16* __restrict__ W, const float* __restrict__ bias,
        float* __restrict__ out) {
    __shared__ __align__(16) u16 smem[32768];   // 4 ring buffers x 16 KB
    int m0 = blockIdx.x * 128, n0 = blockIdx.y * 128;
    f32x4 acc[4][4];
    #pragma unroll
    for (int i = 0; i < 4; i++)
        #pragma unroll
        for (int j = 0; j < 4; j++) acc[i][j] = (f32x4){0.f, 0.f, 0.f, 0.f};
    gemm128_mainloop(A + m0 * 1536, W + n0 * 1536, 1536, acc, smem);

    int tid = threadIdx.x, lane = tid & 63, wave = tid >> 6;
    int wm = (wave >> 1) * 64, wn = (wave & 1) * 64, fm = lane & 15, fq = lane >> 4;
    #pragma unroll
    for (int mi = 0; mi < 4; mi++) {
        #pragma unroll
        for (int ni = 0; ni < 4; ni++) {
            int col = n0 + wn + 16 * ni + fm;
            int rbase = m0 + wm + 16 * mi + fq * 4;
            float bv = bias[col];
            #pragma unroll
            for (int reg = 0; reg < 4; reg++) {
                int row = rbase + reg;
                out[row * 1536 + col] = acc[mi][ni][reg] + bv;
            }
        }
    }
}

// ------------------------------------------------------------------
extern "C" void kernel_launch(void* const* d_in, const int* in_sizes, int n_in,
                              void* d_out, int out_size, void* d_ws, size_t ws_size,
                              hipStream_t stream) {
    (void)in_sizes; (void)n_in; (void)out_size; (void)ws_size;
    const float* x    = (const float*)d_in[0];
    const float* Wq   = (const float*)d_in[1];
    const float* Wk   = (const float*)d_in[2];
    const float* Wv   = (const float*)d_in[3];
    const float* Wrel = (const float*)d_in[4];
    const float* Wout = (const float*)d_in[5];
    const float* bout = (const float*)d_in[6];
    const float* cb   = (const float*)d_in[7];
    const float* pb   = (const float*)d_in[8];

    // bf16 workspace layout (u16 units)
    u16* xb  = (u16*)d_ws;                // 2*1536*1536 = 4,718,592
    u16* wqb = xb  + 4718592;             // 512*1536    =   786,432
    u16* wkb = wqb + 786432;              //               786,432
    u16* wvb = wkb + 786432;              // 1536*1536   = 2,359,296
    u16* wob = wvb + 2359296;             // 1536*1536   = 2,359,296
    u16* qc  = wob + 2359296;             // 2*8*1536*64 = 1,572,864
    u16* qp  = qc + 1572864;
    u16* kw  = qp + 1572864;
    u16* vt  = kw + 1572864;              // 2*8*192*1536 = 4,718,592
    u16* rk  = vt + 4718592;              // 8*3072*64    = 1,572,864
    u16* ao  = rk + 1572864;              // 3072*1536    = 4,718,592
    float* out = (float*)d_out;

    convert_kernel<<<dim3(1024), dim3(256), 0, stream>>>(x, Wq, Wk, Wv, Wout, xb);
    embed_relk_kernel<<<dim3(192), dim3(256), 0, stream>>>(Wrel, rk);
    gemm_qkv_kernel<<<dim3(24, 20), dim3(256), 0, stream>>>(xb, wqb, wkb, wvb, cb, pb, qc, qp, kw, vt);
    attn_kernel<<<dim3(48, 16), dim3(256), 0, stream>>>(qc, qp, kw, vt, rk, ao);
    gemm_out_kernel<<<dim3(24, 12), dim3(256), 0, stream>>>(ao, wob, bout, out);
}

// Round 13
// 299.537 us; speedup vs baseline: 1.0992x; 1.0992x over previous
//
#include <hip/hip_runtime.h>
#include <cmath>

typedef unsigned short u16;
typedef unsigned int u32;
typedef short frag8 __attribute__((ext_vector_type(8)));   // 8 bf16 = 4 VGPRs
typedef float f32x4 __attribute__((ext_vector_type(4)));

#define DEVINL __device__ __forceinline__

DEVINL float bf2f(u16 v) { return __uint_as_float(((u32)v) << 16); }
DEVINL u16 f2bf(float f) {
    u32 u = __float_as_uint(f);
    u32 r = (u + 0x7fffu + ((u >> 16) & 1u)) >> 16;   // RNE
    return (u16)r;
}
DEVINL u32 pack2(float a, float b) { return (u32)f2bf(a) | ((u32)f2bf(b) << 16); }
DEVINL void async_copy16(const u16* g, u16* l) {
    __builtin_amdgcn_global_load_lds((const __attribute__((address_space(1))) u32*)g,
                                     (__attribute__((address_space(3))) u32*)l, 16, 0, 0);
}
DEVINL f32x4 mfma_bf16(frag8 a, frag8 b, f32x4 c) {
    return __builtin_amdgcn_mfma_f32_16x16x32_bf16(a, b, c, 0, 0, 0);
}
// Counted VMEM wait (literal N). Memory clobber pins surrounding memory ops.
#define VMCNT(N) asm volatile("s_waitcnt vmcnt(" #N ")" ::: "memory")
// Raw barrier: orders LDS (lgkmcnt(0) + s_barrier) WITHOUT draining vmcnt —
// prefetched global_load_lds stay in flight across it. (__syncthreads would
// emit s_waitcnt vmcnt(0) and kill the pipeline.)
DEVINL void bar_raw() {
    asm volatile("s_waitcnt lgkmcnt(0)" ::: "memory");
    __builtin_amdgcn_s_barrier();
    asm volatile("" ::: "memory");
}

// ------------------------------------------------------------------
// Kernel 0: f32 -> bf16 conversion of x, Wq, Wk, Wv, Wout into ws.
// ------------------------------------------------------------------
__global__ __launch_bounds__(256) void convert_kernel(
        const float* __restrict__ s0, const float* __restrict__ s1,
        const float* __restrict__ s2, const float* __restrict__ s3,
        const float* __restrict__ s4, u16* __restrict__ dst) {
    const int c0 = 589824, c1 = 98304, c2 = 98304, c3 = 294912;  // chunks of 8
    const int total = 1376256;
    for (int c = blockIdx.x * blockDim.x + threadIdx.x; c < total;
         c += gridDim.x * blockDim.x) {
        const float* src; int off;
        if (c < c0) { src = s0; off = c; }
        else if (c < c0 + c1) { src = s1; off = c - c0; }
        else if (c < c0 + c1 + c2) { src = s2; off = c - c0 - c1; }
        else if (c < c0 + c1 + c2 + c3) { src = s3; off = c - c0 - c1 - c2; }
        else { src = s4; off = c - c0 - c1 - c2 - c3; }
        float4 a = ((const float4*)src)[off * 2];
        float4 b = ((const float4*)src)[off * 2 + 1];
        uint4 o;
        o.x = pack2(a.x, a.y); o.y = pack2(a.z, a.w);
        o.z = pack2(b.x, b.y); o.w = pack2(b.z, b.w);
        ((uint4*)dst)[c] = o;
    }
}

// ------------------------------------------------------------------
// Kernel 1: positional embedding features fused with rel_k projection
// rel_k layout: [h][3072][64] bf16 (row 3071 = pad, computed anyway)
// ------------------------------------------------------------------
DEVINL double lgamma_stirling(double z) {
    double zi = 1.0 / z, zi2 = zi * zi;
    return (z - 0.5) * log(z) - z + 0.91893853320467274178
         + zi * (1.0 / 12.0) - zi * zi2 * (1.0 / 360.0) + zi * zi2 * zi2 * (1.0 / 1260.0);
}

__global__ __launch_bounds__(256) void embed_relk_kernel(const float* __restrict__ Wrel,
                                                         u16* __restrict__ relk) {
    __shared__ float pos[16][192];
    __shared__ float inv_hl[32], cwid[32], cm1[32], rateS[32];
    __shared__ double lognS[32];
    __shared__ float gmax[16];
    int t = threadIdx.x;
    int u0b = blockIdx.x * 16;

    if (t < 32) {
        double step = (10.584962500721156 - 3.0) / 31.0;   // log2(1536)
        double hl = exp2(3.0 + t * step);
        inv_hl[t] = (float)(1.0 / hl);
        cwid[t] = exp2f((float)(t + 1)) - 1.0f;            // 2^(t+1)-1
        double mean = 48.0 * (t + 1);                      // linspace(48,1536,32)
        double conc = (mean / 24.0) * (mean / 24.0);
        double rate = mean / 576.0;
        cm1[t] = (float)(conc - 1.0);
        rateS[t] = (float)rate;
        lognS[t] = lgamma_stirling(conc) - conc * log(rate);
    }
    __syncthreads();

    for (int idx = t; idx < 512; idx += 256) {
        int ul = idx >> 5, bs = idx & 31;
        int dist = u0b + ul - 1535;
        float ad = fabsf((float)dist);
        pos[ul][bs] = exp2f(-ad * inv_hl[bs]);
        pos[ul][32 + bs] = (cwid[bs] > ad) ? 1.0f : 0.0f;
        double prob = 0.0;
        if (dist != 0) {
            double adD = (double)ad;
            prob = exp((double)cm1[bs] * log(adD) - (double)rateS[bs] * adD - lognS[bs]);
        }
        pos[ul][64 + bs] = (float)(prob + 1e-8);
    }
    __syncthreads();
    if (t < 16) {
        float g = 0.f;
        #pragma unroll
        for (int bsx = 0; bsx < 32; bsx++) g = fmaxf(g, pos[t][64 + bsx]);
        gmax[t] = g;
    }
    __syncthreads();
    for (int idx = t; idx < 16 * 96; idx += 256) {
        int ul = idx / 96, f = idx - ul * 96;
        float v = pos[ul][f];
        if (f >= 64) { v = v / gmax[ul]; pos[ul][f] = v; }
        int dist = u0b + ul - 1535;
        float sg = (dist > 0) ? 1.f : ((dist < 0) ? -1.f : 0.f);
        pos[ul][96 + f] = sg * v;
    }
    __syncthreads();

    // project: rel_k[u][e] = sum_f pos[u][f] * Wrel[e][f]; thread owns 2 e-cols
    int e0 = t * 2;
    const float* w0 = Wrel + e0 * 192;
    const float* w1 = w0 + 192;
    float a0[16], a1[16];
    #pragma unroll
    for (int ul = 0; ul < 16; ul++) { a0[ul] = 0.f; a1[ul] = 0.f; }
    for (int f = 0; f < 192; f++) {
        float wa = w0[f], wb = w1[f];
        #pragma unroll
        for (int ul = 0; ul < 16; ul++) {
            float p = pos[ul][f];
            a0[ul] = fmaf(p, wa, a0[ul]);
            a1[ul] = fmaf(p, wb, a1[ul]);
        }
    }
    int h0 = e0 >> 6, d0 = e0 & 63;
    int h1 = (e0 + 1) >> 6, d1 = (e0 + 1) & 63;
    for (int ul = 0; ul < 16; ul++) {
        int u = u0b + ul;
        relk[(h0 * 3072 + u) * 64 + d0] = f2bf(a0[ul]);
        relk[(h1 * 3072 + u) * 64 + d1] = f2bf(a1[ul]);
    }
}

// ------------------------------------------------------------------
// Shared 128x128 BT-GEMM mainloop, K contiguous in both operands.
// Ring-4 LDS buffers, DEPTH-3 counted-vmcnt prefetch (verified r7).
// Identity block mapping (r10: chunked swizzle neutral within noise).
// ------------------------------------------------------------------
DEVINL void gemm128_stage(const u16* __restrict__ A, const u16* __restrict__ B,
                          int K, int k0, u16* buf, int tid) {
    #pragma unroll
    for (int p = 0; p < 2; p++) {     // 4 loads/thread (2 A + 2 B)
        int e = (p * 256 + tid) * 8;
        int r = e >> 5, c = e & 31;
        async_copy16(A + r * K + k0 + c, buf + e);            // As @ buf
        async_copy16(B + r * K + k0 + c, buf + 4096 + e);     // Bs @ buf+4096
    }
}

DEVINL void gemm128_mainloop(const u16* __restrict__ A, const u16* __restrict__ B,
                             int K, f32x4 acc[4][4], u16* smem) {
    int tid = threadIdx.x;
    int lane = tid & 63, wave = tid >> 6;
    int wm = (wave >> 1) * 64, wn = (wave & 1) * 64;
    int fm = lane & 15, fq = lane >> 4;
    const int NT = K >> 5;   // 48
    gemm128_stage(A, B, K, 0,  smem,         tid);   // prologue: 3 tiles
    gemm128_stage(A, B, K, 32, smem + 8192,  tid);   // in flight (12 loads)
    gemm128_stage(A, B, K, 64, smem + 16384, tid);
    for (int t = 0; t < NT; t++) {
        u16* cur = smem + (t & 3) * 8192;
        if (t + 3 < NT) {
            gemm128_stage(A, B, K, (t + 3) * 32, smem + ((t + 3) & 3) * 8192, tid);
            VMCNT(12);    // tile t landed; t+1..t+3 (12 loads) in flight
        } else if (t + 2 < NT) {
            VMCNT(8);
        } else if (t + 1 < NT) {
            VMCNT(4);
        } else {
            VMCNT(0);
        }
        bar_raw();        // every wave waited its own loads -> tile visible
        frag8 af[4], bfr[4];
        #pragma unroll
        for (int mi = 0; mi < 4; mi++) af[mi] = *(const frag8*)&cur[(wm + 16 * mi + fm) * 32 + fq * 8];
        #pragma unroll
        for (int ni = 0; ni < 4; ni++) bfr[ni] = *(const frag8*)&cur[4096 + (wn + 16 * ni + fm) * 32 + fq * 8];
        #pragma unroll
        for (int mi = 0; mi < 4; mi++)
            #pragma unroll
            for (int ni = 0; ni < 4; ni++)
                acc[mi][ni] = mfma_bf16(af[mi], bfr[ni], acc[mi][ni]);
        bar_raw();        // reads done; iter t+1 may overwrite buf[(t+4)&3]
    }
}

// ------------------------------------------------------------------
// Kernel 2: fused QKV projection. N=2560 = [q 512 | k 512 | v 1536]
// qc/qp/k layout [b][h][n][64]; V stored transposed [b][h][192][n]
// ------------------------------------------------------------------
__global__ __launch_bounds__(256) void gemm_qkv_kernel(
        const u16* __restrict__ X, const u16* __restrict__ Wq, const u16* __restrict__ Wk,
        const u16* __restrict__ Wv, const float* __restrict__ cbias, const float* __restrict__ pbias,
        u16* __restrict__ qc, u16* __restrict__ qp, u16* __restrict__ kws, u16* __restrict__ vt) {
    __shared__ __align__(16) u16 smem[32768];   // 4 ring buffers x 16 KB
    int m0 = blockIdx.x * 128, n0 = blockIdx.y * 128;
    const u16* Bp; int brow;
    if (n0 < 512)       { Bp = Wq; brow = n0; }
    else if (n0 < 1024) { Bp = Wk; brow = n0 - 512; }
    else                { Bp = Wv; brow = n0 - 1024; }
    f32x4 acc[4][4];
    #pragma unroll
    for (int i = 0; i < 4; i++)
        #pragma unroll
        for (int j = 0; j < 4; j++) acc[i][j] = (f32x4){0.f, 0.f, 0.f, 0.f};
    gemm128_mainloop(X + m0 * 1536, Bp + brow * 1536, 1536, acc, smem);

    int tid = threadIdx.x, lane = tid & 63, wave = tid >> 6;
    int wm = (wave >> 1) * 64, wn = (wave & 1) * 64, fm = lane & 15, fq = lane >> 4;
    #pragma unroll
    for (int mi = 0; mi < 4; mi++) {
        #pragma unroll
        for (int ni = 0; ni < 4; ni++) {
            int col = n0 + wn + 16 * ni + fm;
            int rbase = m0 + wm + 16 * mi + fq * 4;
            #pragma unroll
            for (int reg = 0; reg < 4; reg++) {
                int row = rbase + reg;
                float v = acc[mi][ni][reg];
                int b = row >= 1536 ? 1 : 0;
                int i = row - b * 1536;
                if (n0 < 512) {
                    float qv = v * 0.125f;
                    int idx = ((b * 8 + (col >> 6)) * 1536 + i) * 64 + (col & 63);
                    qc[idx] = f2bf(qv + cbias[col]);
                    qp[idx] = f2bf(qv + pbias[col]);
                } else if (n0 < 1024) {
                    int c2 = col - 512;
                    kws[((b * 8 + (c2 >> 6)) * 1536 + i) * 64 + (c2 & 63)] = f2bf(v);
                } else {
                    int c2 = col - 1024;
                    int hh = c2 / 192, dd = c2 - hh * 192;
                    vt[((b * 8 + hh) * 192 + dd) * 1536 + i] = f2bf(v);
                }
            }
        }
    }
}

// ------------------------------------------------------------------
// Kernel 3: flash attention with relative-shift band.
// r12 = EXACT r5 attn kernel (verified best: 93.2 us r5 / 94.8 us r6).
// Post-r5 restructures all regressed under matched environments:
//   r8 (V-direct + unaliased + padded): 113 us (r10, identity env)
//   r11 (all-direct): 127 us
// Mechanism: global_load_lds staging issues dense block-wide 1KB bursts;
// per-lane direct frag loads scatter 16B/lane across 128B-strided rows
// (16 transactions/instr serving 4 lanes each) - worse VMEM efficiency.
// Structure: round-0 staging + XCD swizzle (FETCH 6x down) + T4
// counted-vmcnt pipeline (VMCNT(6) drains only K/relk; V drains at
// VMCNT(0) under softmax) + 5 raw barriers + K/relk(t+1) prefetch
// after B5 into the S/R-aliased region.
// ------------------------------------------------------------------
DEVINL void stage_k(const u16* kP, u16* k_lds, int j0, int tid) {
    #pragma unroll
    for (int p = 0; p < 2; p++) {        // K: 64 rows x 8 chunks, xor-swizzled
        int l = p * 256 + tid, r = l >> 3, c = (l & 7) ^ (r & 7);
        async_copy16(kP + (j0 + r) * 64 + c * 8, k_lds + l * 8);
    }
}
DEVINL void stage_relk(const u16* rkP, u16* relk_lds, int u0, int tid) {
    #pragma unroll
    for (int p = 0; p < 3; p++) {        // relk: 96 rows x 8 chunks
        int l = p * 256 + tid, r = l >> 3, c = (l & 7) ^ (r & 7);
        async_copy16(rkP + (u0 + r) * 64 + c * 8, relk_lds + l * 8);
    }
}
DEVINL void stage_v(const u16* vtP, u16* vt_lds, int j0, int tid) {
    #pragma unroll
    for (int p = 0; p < 6; p++) {        // Vt: 192 rows x 8 chunks
        int l = p * 256 + tid, r = l >> 3, c = (l & 7) ^ (r & 7);
        async_copy16(vtP + r * 1536 + j0 + c * 8, vt_lds + l * 8);
    }
}

__global__ __launch_bounds__(256) void attn_kernel(
        const u16* __restrict__ qc, const u16* __restrict__ qp, const u16* __restrict__ kws,
        const u16* __restrict__ vt, const u16* __restrict__ relk, u16* __restrict__ ao) {
    // carve (u16 units): k 4096 | vt 12288 | relk 6144 | P 2048 | state 192
    // total 24768 u16 = 49536 B  -> 3 blocks/CU
    __shared__ __align__(16) u16 smem[24768];
    u16* k_lds    = smem;                    // [64][64] swizzled; aliased S[32][64] f32
    u16* vt_lds   = smem + 4096;             // [192][64] swizzled ([dv][j])
    u16* relk_lds = smem + 16384;            // [96][64] swizzled; aliased R[32][96] f32
    u16* P_lds    = smem + 22528;            // [32][64], chunk-swizzled
    float* S_lds  = (float*)k_lds;
    float* R_lds  = (float*)relk_lds;
    float* mstate = (float*)(smem + 24576);  // [32]
    float* lstate = mstate + 32;
    float* alpha_lds = lstate + 32;

    const int n = 1536;
    // XCD-aware swizzle (bijective: 768 blocks % 8 == 0): XCD c owns bh
    // {2c,2c+1} entirely -> per-XCD L2 working set ~3.1 MB < 4 MB.
    // [verified r3/r4: FETCH 74 -> 12.4 MB]
    int flat = blockIdx.y * 48 + blockIdx.x;
    int swz  = (flat & 7) * 96 + (flat >> 3);
    int bh = swz / 48;
    int i0 = (swz - bh * 48) * 32;
    int b = bh >> 3, h = bh & 7;
    const u16* qcP = qc + bh * n * 64;
    const u16* qpP = qp + bh * n * 64;
    const u16* kP  = kws + bh * n * 64;
    const u16* vtP = vt + bh * 192 * n;
    const u16* rkP = relk + h * 3072 * 64;

    int tid = threadIdx.x, lane = tid & 63, w = tid >> 6, fm = lane & 15, fq = lane >> 4;
    int sw = fm & 7;   // xor-swizzle key: row&7 == fm&7 for all fragment rows
    if (tid < 32) { mstate[tid] = __int_as_float(0xff800000); lstate[tid] = 0.f; }

    // Q fragments live in registers for the whole block
    frag8 aqc[2][2], aqp[2][2];
    #pragma unroll
    for (int mi = 0; mi < 2; mi++)
        #pragma unroll
        for (int ks = 0; ks < 2; ks++) {
            int off = (i0 + 16 * mi + fm) * 64 + ks * 32 + fq * 8;
            aqc[mi][ks] = *(const frag8*)(qcP + off);
            aqp[mi][ks] = *(const frag8*)(qpP + off);
        }

    f32x4 acc_o[2][3];
    #pragma unroll
    for (int mi = 0; mi < 2; mi++)
        #pragma unroll
        for (int dj = 0; dj < 3; dj++) acc_o[mi][dj] = (f32x4){0.f, 0.f, 0.f, 0.f};

    // R-tile ownership: tv = w + 4tt -> (ui = tv%6, rmi = tv/6)
    int uis[3], rmis[3];
    #pragma unroll
    for (int tt = 0; tt < 3; tt++) {
        int tv = w + tt * 4;
        rmis[tt] = (tv >= 6) ? 1 : 0;
        uis[tt] = tv - rmis[tt] * 6;
    }

    // ---- prologue: stage tile 0's K + relk (5 loads in flight) ----
    stage_k(kP, k_lds, 0, tid);
    stage_relk(rkP, relk_lds, 1504 - i0, tid);

    for (int jt = 0; jt < 24; jt++) {
        int j0 = jt * 64;
        bar_raw();         // B1: prior PV LDS reads complete (vt region safe)
        stage_v(vtP, vt_lds, j0, tid);   // 6 loads; drain at VMCNT(0) below
        VMCNT(6);          // oldest (K/relk for THIS tile, + prologue Q) landed
        bar_raw();         // B2: staged K/relk visible to all waves

        // content logits: wave w owns j-cols 16w..16w+15
        f32x4 acc_s[2];
        acc_s[0] = (f32x4){0.f, 0.f, 0.f, 0.f};
        acc_s[1] = (f32x4){0.f, 0.f, 0.f, 0.f};
        #pragma unroll
        for (int ks = 0; ks < 2; ks++) {
            frag8 bk = *(const frag8*)&k_lds[(16 * w + fm) * 64 + ((ks * 4 + fq) ^ sw) * 8];
            acc_s[0] = mfma_bf16(aqc[0][ks], bk, acc_s[0]);
            acc_s[1] = mfma_bf16(aqc[1][ks], bk, acc_s[1]);
        }
        // rel band R[32][96]: 12 tiles, wave w owns tv = w, w+4, w+8
        f32x4 acc_r[3];
        #pragma unroll
        for (int tt = 0; tt < 3; tt++) {
            acc_r[tt] = (f32x4){0.f, 0.f, 0.f, 0.f};
            #pragma unroll
            for (int ks = 0; ks < 2; ks++) {
                frag8 br = *(const frag8*)&relk_lds[(16 * uis[tt] + fm) * 64 + ((ks * 4 + fq) ^ sw) * 8];
                acc_r[tt] = mfma_bf16(aqp[rmis[tt]][ks], br, acc_r[tt]);
            }
        }
        bar_raw();         // B3: k/relk reads done; safe to overwrite with S/R

        #pragma unroll
        for (int mi = 0; mi < 2; mi++)
            #pragma unroll
            for (int reg = 0; reg < 4; reg++)
                S_lds[(16 * mi + fq * 4 + reg) * 64 + 16 * w + fm] = acc_s[mi][reg];
        #pragma unroll
        for (int tt = 0; tt < 3; tt++)
            #pragma unroll
            for (int reg = 0; reg < 4; reg++)
                R_lds[(16 * rmis[tt] + fq * 4 + reg) * 96 + 16 * uis[tt] + fm] = acc_r[tt][reg];
        bar_raw();         // B4: S and R visible

        // online softmax: 8 threads per row; P chunk-swizzled write
        int li = tid >> 3, c0 = (tid & 7) * 8;
        float sv[8];
        float mx = __int_as_float(0xff800000);
        #pragma unroll
        for (int e = 0; e < 8; e++) {
            int c = c0 + e;
            sv[e] = S_lds[li * 64 + c] + R_lds[li * 96 + c - li + 31];
            mx = fmaxf(mx, sv[e]);
        }
        mx = fmaxf(mx, __shfl_xor(mx, 1));
        mx = fmaxf(mx, __shfl_xor(mx, 2));
        mx = fmaxf(mx, __shfl_xor(mx, 4));
        float mo = mstate[li];
        float mn = fmaxf(mo, mx);
        float al = __expf(mo - mn);
        float pe[8], sum = 0.f;
        #pragma unroll
        for (int e = 0; e < 8; e++) { pe[e] = __expf(sv[e] - mn); sum += pe[e]; }
        {
            uint4 pw;
            pw.x = pack2(pe[0], pe[1]); pw.y = pack2(pe[2], pe[3]);
            pw.z = pack2(pe[4], pe[5]); pw.w = pack2(pe[6], pe[7]);
            int slot = (tid & 7) ^ (li & 7);
            *(uint4*)&P_lds[li * 64 + slot * 8] = pw;
        }
        sum += __shfl_xor(sum, 1);
        sum += __shfl_xor(sum, 2);
        sum += __shfl_xor(sum, 4);
        if ((tid & 7) == 0) {
            mstate[li] = mn;
            lstate[li] = lstate[li] * al + sum;
            alpha_lds[li] = al;
        }
        VMCNT(0);          // V landed (hidden under exchange + softmax)
        bar_raw();         // B5: P, alpha, V visible

        // prefetch next tile's K/relk into the S/R-aliased region
        // (all waves' softmax reads of S/R finished before B5)
        if (jt < 23) {
            stage_k(kP, k_lds, j0 + 64, tid);
            stage_relk(rkP, relk_lds, 1504 - i0 + j0 + 64, tid);
        }

        // PV: wave w owns dv tiles 3w..3w+2
        #pragma unroll
        for (int mi = 0; mi < 2; mi++)
            #pragma unroll
            for (int reg = 0; reg < 4; reg++) {
                float al2 = alpha_lds[16 * mi + fq * 4 + reg];
                #pragma unroll
                for (int dj = 0; dj < 3; dj++) acc_o[mi][dj][reg] *= al2;
            }
        frag8 ap[2][2];
        #pragma unroll
        for (int mi = 0; mi < 2; mi++)
            #pragma unroll
            for (int ks = 0; ks < 2; ks++)
                ap[mi][ks] = *(const frag8*)&P_lds[(16 * mi + fm) * 64 + ((ks * 4 + fq) ^ sw) * 8];
        #pragma unroll
        for (int dj = 0; dj < 3; dj++) {
            #pragma unroll
            for (int ks = 0; ks < 2; ks++) {
                frag8 bv = *(const frag8*)&vt_lds[(16 * (3 * w + dj) + fm) * 64 + ((ks * 4 + fq) ^ sw) * 8];
                acc_o[0][dj] = mfma_bf16(ap[0][ks], bv, acc_o[0][dj]);
                acc_o[1][dj] = mfma_bf16(ap[1][ks], bv, acc_o[1][dj]);
            }
        }
    }

    // epilogue: O / l -> ao[b*1536 + i][h*192 + dv]
    // (lstate writes precede final B5 -> visible here)
    #pragma unroll
    for (int mi = 0; mi < 2; mi++)
        #pragma unroll
        for (int dj = 0; dj < 3; dj++)
            #pragma unroll
            for (int reg = 0; reg < 4; reg++) {
                int rl = 16 * mi + fq * 4 + reg;
                float lsum = lstate[rl];
                int row = b * 1536 + i0 + rl;
                int col = h * 192 + 16 * (3 * w + dj) + fm;
                ao[row * 1536 + col] = f2bf(acc_o[mi][dj][reg] / lsum);
            }
}

// ------------------------------------------------------------------
// Kernel 4: output projection + bias (f32 out)
// ------------------------------------------------------------------
__global__ __launch_bounds__(256) void gemm_out_kernel(
        const u16* __restrict__ A, const u16* __restrict__ W, const float* __restrict__ bias,
        float* __restrict__ out) {
    __shared__ __align__(16) u16 smem[32768];   // 4 ring buffers x 16 KB
    int m0 = blockIdx.x * 128, n0 = blockIdx.y * 128;
    f32x4 acc[4][4];
    #pragma unroll
    for (int i = 0; i < 4; i++)
        #pragma unroll
        for (int j = 0; j < 4; j++) acc[i][j] = (f32x4){0.f, 0.f, 0.f, 0.f};
    gemm128_mainloop(A + m0 * 1536, W + n0 * 1536, 1536, acc, smem);

    int tid = threadIdx.x, lane = tid & 63, wave = tid >> 6;
    int wm = (wave >> 1) * 64, wn = (wave & 1) * 64, fm = lane & 15, fq = lane >> 4;
    #pragma unroll
    for (int mi = 0; mi < 4; mi++) {
        #pragma unroll
        for (int ni = 0; ni < 4; ni++) {
            int col = n0 + wn + 16 * ni + fm;
            int rbase = m0 + wm + 16 * mi + fq * 4;
            float bv = bias[col];
            #pragma unroll
            for (int reg = 0; reg < 4; reg++) {
                int row = rbase + reg;
                out[row * 1536 + col] = acc[mi][ni][reg] + bv;
            }
        }
    }
}

// ------------------------------------------------------------------
extern "C" void kernel_launch(void* const* d_in, const int* in_sizes, int n_in,
                              void* d_out, int out_size, void* d_ws, size_t ws_size,
                              hipStream_t stream) {
    (void)in_sizes; (void)n_in; (void)out_size; (void)ws_size;
    const float* x    = (const float*)d_in[0];
    const float* Wq   = (const float*)d_in[1];
    const float* Wk   = (const float*)d_in[2];
    const float* Wv   = (const float*)d_in[3];
    const float* Wrel = (const float*)d_in[4];
    const float* Wout = (const float*)d_in[5];
    const float* bout = (const float*)d_in[6];
    const float* cb   = (const float*)d_in[7];
    const float* pb   = (const float*)d_in[8];

    // bf16 workspace layout (u16 units)
    u16* xb  = (u16*)d_ws;                // 2*1536*1536 = 4,718,592
    u16* wqb = xb  + 4718592;             // 512*1536    =   786,432
    u16* wkb = wqb + 786432;              //               786,432
    u16* wvb = wkb + 786432;              // 1536*1536   = 2,359,296
    u16* wob = wvb + 2359296;             // 1536*1536   = 2,359,296
    u16* qc  = wob + 2359296;             // 2*8*1536*64 = 1,572,864
    u16* qp  = qc + 1572864;
    u16* kw  = qp + 1572864;
    u16* vt  = kw + 1572864;              // 2*8*192*1536 = 4,718,592
    u16* rk  = vt + 4718592;              // 8*3072*64    = 1,572,864
    u16* ao  = rk + 1572864;              // 3072*1536    = 4,718,592
    float* out = (float*)d_out;

    convert_kernel<<<dim3(1024), dim3(256), 0, stream>>>(x, Wq, Wk, Wv, Wout, xb);
    embed_relk_kernel<<<dim3(192), dim3(256), 0, stream>>>(Wrel, rk);
    gemm_qkv_kernel<<<dim3(24, 20), dim3(256), 0, stream>>>(xb, wqb, wkb, wvb, cb, pb, qc, qp, kw, vt);
    attn_kernel<<<dim3(48, 16), dim3(256), 0, stream>>>(qc, qp, kw, vt, rk, ao);
    gemm_out_kernel<<<dim3(24, 12), dim3(256), 0, stream>>>(ao, wob, bout, out);
}